// Round 4
// baseline (476.854 us; speedup 1.0000x reference)
//
#include <hip/hip_runtime.h>

#define NB 8
#define NC 64
#define NN 4096
#define NO 64
#define KK 20
#define EPSV 1e-5f
#define SLOPE 0.2f

typedef __attribute__((ext_vector_type(8))) short short8x;
typedef __attribute__((ext_vector_type(4))) float float4x;

// ws layout (float words):
// y1   : [B][N][O]            @0         2097152
// y2   : [B][N][O]            @2097152   2097152
// xx   : [B][N]               @4194304   32768
// keyu : [B][N][2][20] u32    @4227072   1310720
// idxu : [B][N][2][20] u16    @5537792   655360 words
// wa   : [C][O]               @6193152   4096
// wb   : [C][O]               @6197248   4096
// xThi : [B][N][C] bf16       @6201344   1048576
// xTmid: [B][N][C] bf16       @7249920   1048576
// xTlo : [B][N][C] bf16       @8298496   1048576

__device__ __forceinline__ unsigned short bfh(float f) {  // fp32 -> bf16 (RNE)
  unsigned u = __float_as_uint(f);
  unsigned r = u + 0x7FFFu + ((u >> 16) & 1u);
  return (unsigned short)(r >> 16);
}

__device__ __forceinline__ unsigned flipf(float f) {
  unsigned u = __float_as_uint(f);
  return u ^ ((unsigned)((int)u >> 31) | 0x80000000u);
}

// inverse of flipf, on raw flipped bits -> float bits
__device__ __forceinline__ unsigned unflipu(unsigned v) {
  return v ^ (0x80000000u | (unsigned)((int)(~v) >> 31));
}

__global__ void k0_wprep(const float* __restrict__ W,
                         float* __restrict__ wa, float* __restrict__ wb) {
  int t = threadIdx.x;
  for (int i = t; i < NC * NO; i += 256) {
    int o = i & 63, c = i >> 6;
    float w1 = W[o * 128 + c];
    float w2 = W[o * 128 + 64 + c];
    wa[i] = w1 - w2;  // [c][o]
    wb[i] = w2;
  }
}

__global__ __launch_bounds__(256) void k1_feat(const float* __restrict__ x,
    const float* __restrict__ waT, const float* __restrict__ wbT,
    float* __restrict__ y1, float* __restrict__ y2, float* __restrict__ xxg,
    unsigned short* __restrict__ xThi, unsigned short* __restrict__ xTmid,
    unsigned short* __restrict__ xTlo) {
  __shared__ __align__(16) float xs[NC * 68];   // [c][n] stride 68
  __shared__ __align__(16) float wa[NC * NO];
  __shared__ __align__(16) float wb[NC * NO];
  int t = threadIdx.x;
  int b = blockIdx.x >> 6;
  int gr0 = (blockIdx.x & 63) << 6;
  const float* xb = x + (size_t)b * NC * NN;
  #pragma unroll
  for (int k = 0; k < 4; ++k) {
    int i4 = t + k * 256;
    int c = i4 >> 4, col4 = (i4 & 15) << 2;
    *(float4*)&xs[c * 68 + col4] = *(const float4*)&xb[(size_t)c * NN + gr0 + col4];
    *(float4*)&wa[c * 64 + col4] = *(const float4*)&waT[c * 64 + col4];
    *(float4*)&wb[c * 64 + col4] = *(const float4*)&wbT[c * 64 + col4];
  }
  __syncthreads();
  if (t < 64) {
    float s = 0.f;
    #pragma unroll
    for (int c = 0; c < NC; ++c) { float v = xs[c * 68 + t]; s = fmaf(v, v, s); }
    xxg[b * NN + gr0 + t] = s;
  }
  int o = t & 63, w = t >> 6;
  for (int j = 0; j < 16; ++j) {
    int n = j * 4 + w;
    float a1 = 0.f, a2 = 0.f;
    #pragma unroll
    for (int c = 0; c < NC; ++c) {
      float xv = xs[c * 68 + n];
      a1 = fmaf(wa[c * 64 + o], xv, a1);
      a2 = fmaf(wb[c * 64 + o], xv, a2);
    }
    size_t base = ((size_t)b * NN + gr0 + n) * NO + o;
    y1[base] = a1;
    y2[base] = a2;
  }
  // 3-level bf16 split (REQUIRED: 2-level flips top-K selections, R10 failed),
  // transposed layout xT[b][n][c]
  int n2 = t >> 2, c0 = (t & 3) << 4;
  short8x vh[2], vm[2], vl[2];
  #pragma unroll
  for (int i = 0; i < 16; ++i) {
    float v = xs[(c0 + i) * 68 + n2];
    unsigned short h = bfh(v);
    float hf = __uint_as_float((unsigned)h << 16);
    float r1 = v - hf;
    unsigned short md = bfh(r1);
    float mf = __uint_as_float((unsigned)md << 16);
    unsigned short lo = bfh(r1 - mf);
    vh[i >> 3][i & 7] = (short)h;
    vm[i >> 3][i & 7] = (short)md;
    vl[i >> 3][i & 7] = (short)lo;
  }
  size_t tb = ((size_t)(b * NN + gr0 + n2)) * 64 + c0;
  *(short8x*)&xThi[tb] = vh[0];  *(short8x*)&xThi[tb + 8] = vh[1];
  *(short8x*)&xTmid[tb] = vm[0]; *(short8x*)&xTmid[tb + 8] = vm[1];
  *(short8x*)&xTlo[tb] = vl[0];  *(short8x*)&xTlo[tb + 8] = vl[1];
}

// ----- MFMA split-bf16 Gram + per-row exact top-K (column half) -----
// grid 1024: blk = b*128 + rowgroup*2 + half (R7-proven ordering, 34MB fetch)
// __launch_bounds__(256,3): cap ~170 VGPR -- lst[20] u64 MUST stay in regs
// (R8/R9 lesson: tighter caps spilled lst to scratch -> 0.8GB HBM traffic)
//
// R11 FAILED (writer-side filter + LDS atomicOr masks): atomics added stalls.
// R12 (291us): padded candU killed swizzle math; bank conflicts 7.1M->3.9M,
//   but VALU-busy time ~unchanged -> dominant cost is the wave-granular
//   divergent 20-deep u64 shift-insert + candU round-trip + barrier (C).
// R13 (this round): SWAP MFMA OPERANDS (attention's T12 trick). With
//   mfma(b_frag, a_frag) the D layout becomes col=lane&15=n-row, so each
//   lane holds 16 candidates (m = 16j + 4*quad + q) OF ITS OWN ROW
//   n = 16w + lm. Bit-identical values (same products, same accum chain),
//   just transposed lane placement. This DELETES: candU entirely (16 flip+
//   store + 4 b128 re-reads per tile), barrier (C), cutq LDS (threshold =
//   min over the row's 4 quad-lanes via 2x shfl_xor), and 18.4KB LDS
//   (43.5 -> 24.8KB -> 4+ blocks/CU). Tile = stage, barrier, MFMA,
//   in-register scan/insert -- no intra-tile sync; one wave's divergent
//   insert overlaps other waves' MFMA. Rare-path key fetch by dynamic index
//   uses a 3-cndmask mux (regs can't be runtime-indexed).
__global__ __launch_bounds__(256, 3) void k2_topk(
    const unsigned short* __restrict__ xThi, const unsigned short* __restrict__ xTmid,
    const unsigned short* __restrict__ xTlo, const float* __restrict__ xxg,
    unsigned* __restrict__ keyuG, unsigned short* __restrict__ idxG) {
  __shared__ __align__(16) unsigned short Rb[3 * 4096];  // 24KB staging hi/mid/lo;
                                                         // merge M u64[32*84]=21.5KB aliases
  __shared__ __align__(16) float xxs[64];

  int t = threadIdx.x;
  int blk = blockIdx.x;
  int b = blk >> 7;
  int rem = blk & 127;
  int rg = rem >> 1, half = rem & 1;
  int gr0 = rg << 6;
  int gc0 = half << 11;
  int w = t >> 6;                               // wave
  int lm = t & 15;                              // lane&15 -> row n = 16w+lm
  int quad = (t >> 4) & 3;                      // quarter: owns m ≡ 4q..4q+3 (mod 16)

  // persistent A-fragments (rows gr0+16w+lm, 3 levels x 2 k-steps)
  size_t abase = ((size_t)(b * NN + gr0 + 16 * w + lm)) * 64;
  short8x Ah[2], Am[2], Al[2];
  #pragma unroll
  for (int ks = 0; ks < 2; ++ks) {
    int co = ks * 32 + quad * 8;
    Ah[ks] = *(const short8x*)&xThi[abase + co];
    Am[ks] = *(const short8x*)&xTmid[abase + co];
    Al[ks] = *(const short8x*)&xTlo[abase + co];
  }

  unsigned long long lst[KK];                   // packed (flip(key)<<12)|m
  #pragma unroll
  for (int j = 0; j < KK; ++j) lst[j] = ~0ull;

  size_t bbase = (size_t)(b * NN) * 64;

  for (int mt = 0; mt < 32; ++mt) {
    int gm0 = gc0 + (mt << 6);
    __syncthreads();  // (A) prev tile's Rb/xxs reads done
    #pragma unroll
    for (int lvl = 0; lvl < 3; ++lvl) {
      const unsigned short* src = (lvl == 0) ? xThi : (lvl == 1) ? xTmid : xTlo;
      unsigned short* dst = Rb + lvl * 4096;
      #pragma unroll
      for (int p = 0; p < 2; ++p) {
        int idx = p * 256 + t;
        int n = idx >> 3, o = idx & 7;
        *(short8x*)&dst[n * 64 + ((o + n) & 7) * 8] =
            *(const short8x*)&src[bbase + (size_t)(gm0 + n) * 64 + o * 8];
      }
    }
    if (t < 16) *(float4*)&xxs[t * 4] = *(const float4*)&xxg[b * NN + gm0 + t * 4];
    __syncthreads();  // (B) Rb + xxs ready

    float4x acc[4];
    #pragma unroll
    for (int j = 0; j < 4; ++j) acc[j] = (float4x){0.f, 0.f, 0.f, 0.f};

    const unsigned short* RbH = Rb;
    const unsigned short* RbM = Rb + 4096;
    const unsigned short* RbL = Rb + 8192;
    #pragma unroll
    for (int ks = 0; ks < 2; ++ks) {
      #pragma unroll
      for (int j = 0; j < 4; ++j) {
        int n = 16 * j + lm;
        int off = n * 64 + ((ks * 4 + quad + n) & 7) * 8;
        short8x bh = *(const short8x*)&RbH[off];
        short8x bm = *(const short8x*)&RbM[off];
        short8x bl = *(const short8x*)&RbL[off];
        // swapped operand order (R13): D col=lane&15 = n-row, row = m-col.
        // Same product pairs/order as before -> bit-identical sums.
        acc[j] = __builtin_amdgcn_mfma_f32_16x16x32_bf16(bm, Am[ks], acc[j], 0, 0, 0);
        acc[j] = __builtin_amdgcn_mfma_f32_16x16x32_bf16(bl, Ah[ks], acc[j], 0, 0, 0);
        acc[j] = __builtin_amdgcn_mfma_f32_16x16x32_bf16(bh, Al[ks], acc[j], 0, 0, 0);
        acc[j] = __builtin_amdgcn_mfma_f32_16x16x32_bf16(bm, Ah[ks], acc[j], 0, 0, 0);
        acc[j] = __builtin_amdgcn_mfma_f32_16x16x32_bf16(bh, Am[ks], acc[j], 0, 0, 0);
        acc[j] = __builtin_amdgcn_mfma_f32_16x16x32_bf16(bh, Ah[ks], acc[j], 0, 0, 0);
      }
    }

    // per-lane: acc[j][q] = Gram(n = gr0+16w+lm, m = gm0 + 16j + 4*quad + q)
    // threshold: min over the row's 4 quad-lanes of own 20th-best (float dom.)
    unsigned own19u = (unsigned)(lst[KK - 1] >> 12);
    own19u = min(own19u, 0xFF7FFFFFu);  // clamp sentinel -> FLT_MAX, not NaN
    float thr = __uint_as_float(unflipu(own19u));
    thr = fminf(thr, __shfl_xor(thr, 16));
    thr = fminf(thr, __shfl_xor(thr, 32));

    float key[16];
    unsigned mask = 0;
    #pragma unroll
    for (int j = 0; j < 4; ++j) {
      float4 xq = *(const float4*)&xxs[16 * j + 4 * quad];  // broadcast b128
      const float* xqp = (const float*)&xq;
      #pragma unroll
      for (int q = 0; q < 4; ++q) {
        float kv = fmaf(-2.f, acc[j][q], xqp[q]);
        key[4 * j + q] = kv;
        mask |= (unsigned)(kv <= thr) << (4 * j + q);
      }
    }

    // rare path: row-level bound guarantees any final-top-20 candidate passes;
    // exact u64 check rejects extras. 3-cndmask mux fetches key[e].
    #pragma unroll
    for (int j = 0; j < 4; ++j) {
      unsigned sm = (mask >> (4 * j)) & 0xFu;
      while (sm) {
        int e = __builtin_ctz(sm);
        sm &= sm - 1;
        float k01 = (e & 2) ? key[4 * j + 3] : key[4 * j + 1];
        float k00 = (e & 2) ? key[4 * j + 2] : key[4 * j + 0];
        float kv = (e & 1) ? k01 : k00;
        unsigned ku = flipf(kv);
        int c = 16 * j + (quad << 2) + e;
        unsigned long long p = ((unsigned long long)ku << 12) | (unsigned)(gm0 + c);
        if (p < lst[KK - 1]) {
          #pragma unroll
          for (int jj = KK - 1; jj >= 1; --jj) {
            bool sh = p < lst[jj - 1];
            unsigned long long cur = (p < lst[jj]) ? p : lst[jj];
            lst[jj] = sh ? lst[jj - 1] : cur;
          }
          if (p < lst[0]) lst[0] = p;
        }
      }
    }
  }

  // two-phase merge (rows 0-31, then 32-63): M = u64[32][84] aliases Rb (dead now)
  int orow = 16 * w + lm, oq = quad;            // owner (row, quarter)
  unsigned long long* M = (unsigned long long*)Rb;
  #pragma unroll 1
  for (int ph = 0; ph < 2; ++ph) {
    __syncthreads();
    if ((orow >> 5) == ph) {
      int r5 = orow & 31;
      #pragma unroll
      for (int k = 0; k < KK; ++k) M[r5 * 84 + oq * 21 + k] = lst[k];
      M[r5 * 84 + oq * 21 + KK] = ~0ull;
    }
    __syncthreads();
    if (t < 32) {
      int h0 = 0, h1 = 0, h2 = 0, h3 = 0;
      int rb = t * 84;
      int row = ph * 32 + t;
      size_t base = ((size_t)(b * NN + gr0 + row) * 2 + half) * KK;
      for (int k = 0; k < KK; ++k) {
        unsigned long long v0m = M[rb + h0];
        unsigned long long v1m = M[rb + 21 + h1];
        unsigned long long v2m = M[rb + 42 + h2];
        unsigned long long v3m = M[rb + 63 + h3];
        unsigned long long bv = v0m; int bq = 0;
        if (v1m < bv) { bv = v1m; bq = 1; }
        if (v2m < bv) { bv = v2m; bq = 2; }
        if (v3m < bv) { bv = v3m; bq = 3; }
        keyuG[base + k] = (unsigned)(bv >> 12);
        idxG[base + k] = (unsigned short)(bv & 0xFFFu);
        if (bq == 0) h0++; else if (bq == 1) h1++; else if (bq == 2) h2++; else h3++;
      }
    }
  }
}

__global__ __launch_bounds__(256) void k3_out(const float* __restrict__ y1,
    const float* __restrict__ y2, const unsigned* __restrict__ keyuG,
    const unsigned short* __restrict__ idxG,
    const float* __restrict__ gamma, const float* __restrict__ beta,
    const float* __restrict__ rmean, const float* __restrict__ rvar,
    float* __restrict__ out) {
  __shared__ int sidx[64 * KK];
  __shared__ float ot[64 * 65];  // [o][n], pad 65
  int t = threadIdx.x;
  int b = blockIdx.x >> 6;
  int gr0 = (blockIdx.x & 63) << 6;
  if (t < 64) {  // 2-way merge of column-half lists
    size_t base0 = ((size_t)(b * NN + gr0 + t) * 2) * KK;
    size_t base1 = base0 + KK;
    int h0 = 0, h1 = 0;
    for (int k = 0; k < KK; ++k) {
      int a0 = h0 < KK ? h0 : KK - 1;
      int a1 = h1 < KK ? h1 : KK - 1;
      unsigned k0v = keyuG[base0 + a0]; unsigned i0 = idxG[base0 + a0];
      unsigned k1v = keyuG[base1 + a1]; unsigned i1 = idxG[base1 + a1];
      bool take0 = (h1 >= KK) ||
                   ((h0 < KK) && (k0v < k1v || (k0v == k1v && i0 < i1)));
      sidx[t * KK + k] = take0 ? (int)i0 : (int)i1;
      if (take0) h0++; else h1++;
    }
  }
  int l = t & 63, w = t >> 6;
  float sc = gamma[l] * rsqrtf(rvar[l] + EPSV);
  float tt = fmaf(-rmean[l], sc, beta[l]);
  __syncthreads();
  const float* y2b = y2 + (size_t)b * NN * NO;
  for (int rr = 0; rr < 16; ++rr) {
    int row = w * 16 + rr;
    float v1 = y1[((size_t)b * NN + gr0 + row) * NO + l];
    int mk[KK];
    #pragma unroll
    for (int k = 0; k < KK; ++k) mk[k] = sidx[row * KK + k];
    float vv[KK];
    #pragma unroll
    for (int k = 0; k < KK; ++k) vv[k] = y2b[(size_t)mk[k] * NO + l];  // 20 in flight
    float best = -3.4e38f;
    #pragma unroll
    for (int k = 0; k < KK; ++k) {
      float v = v1 + vv[k];
      v = fmaf(v, sc, tt);
      v = v >= 0.f ? v : SLOPE * v;
      best = fmaxf(best, v);
    }
    ot[l * 65 + row] = best;
  }
  __syncthreads();
  float* ob = out + (size_t)b * NO * NN;
  for (int i = t; i < 4096; i += 256) {
    int o = i >> 6, n = i & 63;
    ob[(size_t)o * NN + gr0 + n] = ot[o * 65 + n];  // coalesced
  }
}

extern "C" void kernel_launch(void* const* d_in, const int* in_sizes, int n_in,
                              void* d_out, int out_size, void* d_ws, size_t ws_size,
                              hipStream_t stream) {
  const float* x     = (const float*)d_in[0];
  const float* W     = (const float*)d_in[1];
  const float* gamma = (const float*)d_in[2];
  const float* beta  = (const float*)d_in[3];
  const float* rmean = (const float*)d_in[4];
  const float* rvar  = (const float*)d_in[5];
  float* ws  = (float*)d_ws;
  float* y1    = ws;
  float* y2    = ws + 2097152;
  float* xx    = ws + 4194304;
  unsigned* keyu = (unsigned*)(ws + 4227072);
  unsigned short* idxu = (unsigned short*)(ws + 5537792);
  float* wa    = ws + 6193152;
  float* wb    = ws + 6197248;
  unsigned short* xThi  = (unsigned short*)(ws + 6201344);
  unsigned short* xTmid = (unsigned short*)(ws + 7249920);
  unsigned short* xTlo  = (unsigned short*)(ws + 8298496);
  float* out = (float*)d_out;

  hipLaunchKernelGGL(k0_wprep, dim3(1),    dim3(256), 0, stream, W, wa, wb);
  hipLaunchKernelGGL(k1_feat,  dim3(512),  dim3(256), 0, stream, x, wa, wb, y1, y2, xx,
                     xThi, xTmid, xTlo);
  hipLaunchKernelGGL(k2_topk,  dim3(1024), dim3(256), 0, stream, xThi, xTmid, xTlo,
                     xx, keyu, idxu);
  hipLaunchKernelGGL(k3_out,   dim3(512),  dim3(256), 0, stream, y1, y2, keyu, idxu,
                     gamma, beta, rmean, rvar, out);
}

// Round 5
// 402.334 us; speedup vs baseline: 1.1852x; 1.1852x over previous
//
#include <hip/hip_runtime.h>

#define NB 8
#define NC 64
#define NN 4096
#define NO 64
#define KK 20
#define EPSV 1e-5f
#define SLOPE 0.2f

typedef __attribute__((ext_vector_type(8))) short short8x;
typedef __attribute__((ext_vector_type(4))) float float4x;

// ws layout (float words):
// y1   : [B][N][O]            @0         2097152
// y2   : [B][N][O]            @2097152   2097152
// xx   : [B][N]               @4194304   32768
// keyu : [B][N][2][20] u32    @4227072   1310720
// idxu : [B][N][2][20] u16    @5537792   655360 words
// wa   : [C][O]               @6193152   4096
// wb   : [C][O]               @6197248   4096
// xThi : [B][N][C] bf16       @6201344   1048576
// xTmid: [B][N][C] bf16       @7249920   1048576
// xTlo : [B][N][C] bf16       @8298496   1048576

__device__ __forceinline__ unsigned short bfh(float f) {  // fp32 -> bf16 (RNE)
  unsigned u = __float_as_uint(f);
  unsigned r = u + 0x7FFFu + ((u >> 16) & 1u);
  return (unsigned short)(r >> 16);
}

__device__ __forceinline__ unsigned flipf(float f) {
  unsigned u = __float_as_uint(f);
  return u ^ ((unsigned)((int)u >> 31) | 0x80000000u);
}

// inverse of flipf, on raw flipped bits -> float bits
__device__ __forceinline__ unsigned unflipu(unsigned v) {
  return v ^ (0x80000000u | (unsigned)((int)(~v) >> 31));
}

__global__ void k0_wprep(const float* __restrict__ W,
                         float* __restrict__ wa, float* __restrict__ wb) {
  int t = threadIdx.x;
  for (int i = t; i < NC * NO; i += 256) {
    int o = i & 63, c = i >> 6;
    float w1 = W[o * 128 + c];
    float w2 = W[o * 128 + 64 + c];
    wa[i] = w1 - w2;  // [c][o]
    wb[i] = w2;
  }
}

__global__ __launch_bounds__(256) void k1_feat(const float* __restrict__ x,
    const float* __restrict__ waT, const float* __restrict__ wbT,
    float* __restrict__ y1, float* __restrict__ y2, float* __restrict__ xxg,
    unsigned short* __restrict__ xThi, unsigned short* __restrict__ xTmid,
    unsigned short* __restrict__ xTlo) {
  __shared__ __align__(16) float xs[NC * 68];   // [c][n] stride 68
  __shared__ __align__(16) float wa[NC * NO];
  __shared__ __align__(16) float wb[NC * NO];
  int t = threadIdx.x;
  int b = blockIdx.x >> 6;
  int gr0 = (blockIdx.x & 63) << 6;
  const float* xb = x + (size_t)b * NC * NN;
  #pragma unroll
  for (int k = 0; k < 4; ++k) {
    int i4 = t + k * 256;
    int c = i4 >> 4, col4 = (i4 & 15) << 2;
    *(float4*)&xs[c * 68 + col4] = *(const float4*)&xb[(size_t)c * NN + gr0 + col4];
    *(float4*)&wa[c * 64 + col4] = *(const float4*)&waT[c * 64 + col4];
    *(float4*)&wb[c * 64 + col4] = *(const float4*)&wbT[c * 64 + col4];
  }
  __syncthreads();
  if (t < 64) {
    float s = 0.f;
    #pragma unroll
    for (int c = 0; c < NC; ++c) { float v = xs[c * 68 + t]; s = fmaf(v, v, s); }
    xxg[b * NN + gr0 + t] = s;
  }
  int o = t & 63, w = t >> 6;
  for (int j = 0; j < 16; ++j) {
    int n = j * 4 + w;
    float a1 = 0.f, a2 = 0.f;
    #pragma unroll
    for (int c = 0; c < NC; ++c) {
      float xv = xs[c * 68 + n];
      a1 = fmaf(wa[c * 64 + o], xv, a1);
      a2 = fmaf(wb[c * 64 + o], xv, a2);
    }
    size_t base = ((size_t)b * NN + gr0 + n) * NO + o;
    y1[base] = a1;
    y2[base] = a2;
  }
  // 3-level bf16 split (REQUIRED: 2-level flips top-K selections, R10 failed),
  // transposed layout xT[b][n][c]
  int n2 = t >> 2, c0 = (t & 3) << 4;
  short8x vh[2], vm[2], vl[2];
  #pragma unroll
  for (int i = 0; i < 16; ++i) {
    float v = xs[(c0 + i) * 68 + n2];
    unsigned short h = bfh(v);
    float hf = __uint_as_float((unsigned)h << 16);
    float r1 = v - hf;
    unsigned short md = bfh(r1);
    float mf = __uint_as_float((unsigned)md << 16);
    unsigned short lo = bfh(r1 - mf);
    vh[i >> 3][i & 7] = (short)h;
    vm[i >> 3][i & 7] = (short)md;
    vl[i >> 3][i & 7] = (short)lo;
  }
  size_t tb = ((size_t)(b * NN + gr0 + n2)) * 64 + c0;
  *(short8x*)&xThi[tb] = vh[0];  *(short8x*)&xThi[tb + 8] = vh[1];
  *(short8x*)&xTmid[tb] = vm[0]; *(short8x*)&xTmid[tb + 8] = vm[1];
  *(short8x*)&xTlo[tb] = vl[0];  *(short8x*)&xTlo[tb + 8] = vl[1];
}

// ----- MFMA split-bf16 Gram + per-row exact top-K (column half) -----
// grid 1024: blk = b*128 + rowgroup*2 + half (R7-proven ordering, 34MB fetch)
//
// R11 FAILED (writer-side filter + LDS atomicOr masks): atomics added stalls.
// R12 (291us): padded candU killed swizzle math; bank conflicts 7.1M->3.9M.
// R13 FAILED on a spill, not the idea: swapped-MFMA lane-local keys passed
//   and deleted candU/cutq/barrier-C, but 4x-replicated insert loops +
//   key[16]+acc live-through + (256,3) pressure made the allocator take the
//   64-VGPR step and spill lst[20] -> WRITE_SIZE 10->155MB, k2 291->379us.
// R14 (this round): same R13 structure, spill-proofed:
//   - ONE insert site: single 16-bit mask, one while loop, key[e] fetched
//     via explicit 15-cndmask binary tree (constant indices only).
//   - __launch_bounds__(256,2): VGPR cap ~256 so lst[20] (40 VGPR) + key[16]
//     stay resident. 8 waves/CU target == R12's MEASURED occupancy (25.7%),
//     so nothing real is lost.
//   - acc dies at key-build, before the scan.
//   Spill tripwire: WRITE_SIZE must be ~10MB (was 155MB spilled).
__global__ __launch_bounds__(256, 2) void k2_topk(
    const unsigned short* __restrict__ xThi, const unsigned short* __restrict__ xTmid,
    const unsigned short* __restrict__ xTlo, const float* __restrict__ xxg,
    unsigned* __restrict__ keyuG, unsigned short* __restrict__ idxG) {
  __shared__ __align__(16) unsigned short Rb[3 * 4096];  // 24KB staging hi/mid/lo;
                                                         // merge M u64[32*84]=21.5KB aliases
  __shared__ __align__(16) float xxs[64];

  int t = threadIdx.x;
  int blk = blockIdx.x;
  int b = blk >> 7;
  int rem = blk & 127;
  int rg = rem >> 1, half = rem & 1;
  int gr0 = rg << 6;
  int gc0 = half << 11;
  int w = t >> 6;                               // wave
  int lm = t & 15;                              // lane&15 -> row n = 16w+lm
  int quad = (t >> 4) & 3;                      // quarter: owns m ≡ 4q..4q+3 (mod 16)

  // persistent A-fragments (rows gr0+16w+lm, 3 levels x 2 k-steps)
  size_t abase = ((size_t)(b * NN + gr0 + 16 * w + lm)) * 64;
  short8x Ah[2], Am[2], Al[2];
  #pragma unroll
  for (int ks = 0; ks < 2; ++ks) {
    int co = ks * 32 + quad * 8;
    Ah[ks] = *(const short8x*)&xThi[abase + co];
    Am[ks] = *(const short8x*)&xTmid[abase + co];
    Al[ks] = *(const short8x*)&xTlo[abase + co];
  }

  unsigned long long lst[KK];                   // packed (flip(key)<<12)|m
  #pragma unroll
  for (int j = 0; j < KK; ++j) lst[j] = ~0ull;

  size_t bbase = (size_t)(b * NN) * 64;

  for (int mt = 0; mt < 32; ++mt) {
    int gm0 = gc0 + (mt << 6);
    __syncthreads();  // (A) prev tile's Rb/xxs reads done
    #pragma unroll
    for (int lvl = 0; lvl < 3; ++lvl) {
      const unsigned short* src = (lvl == 0) ? xThi : (lvl == 1) ? xTmid : xTlo;
      unsigned short* dst = Rb + lvl * 4096;
      #pragma unroll
      for (int p = 0; p < 2; ++p) {
        int idx = p * 256 + t;
        int n = idx >> 3, o = idx & 7;
        *(short8x*)&dst[n * 64 + ((o + n) & 7) * 8] =
            *(const short8x*)&src[bbase + (size_t)(gm0 + n) * 64 + o * 8];
      }
    }
    if (t < 16) *(float4*)&xxs[t * 4] = *(const float4*)&xxg[b * NN + gm0 + t * 4];
    __syncthreads();  // (B) Rb + xxs ready

    float4x acc[4];
    #pragma unroll
    for (int j = 0; j < 4; ++j) acc[j] = (float4x){0.f, 0.f, 0.f, 0.f};

    const unsigned short* RbH = Rb;
    const unsigned short* RbM = Rb + 4096;
    const unsigned short* RbL = Rb + 8192;
    #pragma unroll
    for (int ks = 0; ks < 2; ++ks) {
      #pragma unroll
      for (int j = 0; j < 4; ++j) {
        int n = 16 * j + lm;
        int off = n * 64 + ((ks * 4 + quad + n) & 7) * 8;
        short8x bh = *(const short8x*)&RbH[off];
        short8x bm = *(const short8x*)&RbM[off];
        short8x bl = *(const short8x*)&RbL[off];
        // swapped operand order (R13): D col=lane&15 = n-row, row = m-col.
        // Same product pairs/order as before -> bit-identical sums.
        acc[j] = __builtin_amdgcn_mfma_f32_16x16x32_bf16(bm, Am[ks], acc[j], 0, 0, 0);
        acc[j] = __builtin_amdgcn_mfma_f32_16x16x32_bf16(bl, Ah[ks], acc[j], 0, 0, 0);
        acc[j] = __builtin_amdgcn_mfma_f32_16x16x32_bf16(bh, Al[ks], acc[j], 0, 0, 0);
        acc[j] = __builtin_amdgcn_mfma_f32_16x16x32_bf16(bm, Ah[ks], acc[j], 0, 0, 0);
        acc[j] = __builtin_amdgcn_mfma_f32_16x16x32_bf16(bh, Am[ks], acc[j], 0, 0, 0);
        acc[j] = __builtin_amdgcn_mfma_f32_16x16x32_bf16(bh, Ah[ks], acc[j], 0, 0, 0);
      }
    }

    // per-lane: acc[j][q] = Gram(n = gr0+16w+lm, m = gm0 + 16j + 4*quad + q)
    // threshold: min over the row's 4 quad-lanes of own 20th-best (float dom.)
    unsigned own19u = (unsigned)(lst[KK - 1] >> 12);
    own19u = min(own19u, 0xFF7FFFFFu);  // clamp sentinel -> FLT_MAX, not NaN
    float thr = __uint_as_float(unflipu(own19u));
    thr = fminf(thr, __shfl_xor(thr, 16));
    thr = fminf(thr, __shfl_xor(thr, 32));

    float key[16];
    unsigned mask = 0;
    #pragma unroll
    for (int j = 0; j < 4; ++j) {
      float4 xq = *(const float4*)&xxs[16 * j + 4 * quad];  // broadcast b128
      const float* xqp = (const float*)&xq;
      #pragma unroll
      for (int q = 0; q < 4; ++q) {
        float kv = fmaf(-2.f, acc[j][q], xqp[q]);
        key[4 * j + q] = kv;
        mask |= (unsigned)(kv <= thr) << (4 * j + q);
      }
    }
    // acc dead here.

    // rare path, SINGLE insert site: row-level bound guarantees any
    // final-top-20 candidate passes; exact u64 check rejects extras.
    // key[e] via explicit 15-cndmask tree (constant indices only).
    while (mask) {
      int e = __builtin_ctz(mask);
      mask &= mask - 1;
      float a0 = (e & 1) ? key[1]  : key[0];
      float a1 = (e & 1) ? key[3]  : key[2];
      float a2 = (e & 1) ? key[5]  : key[4];
      float a3 = (e & 1) ? key[7]  : key[6];
      float a4 = (e & 1) ? key[9]  : key[8];
      float a5 = (e & 1) ? key[11] : key[10];
      float a6 = (e & 1) ? key[13] : key[12];
      float a7 = (e & 1) ? key[15] : key[14];
      float b0 = (e & 2) ? a1 : a0;
      float b1 = (e & 2) ? a3 : a2;
      float b2 = (e & 2) ? a5 : a4;
      float b3 = (e & 2) ? a7 : a6;
      float c0v = (e & 4) ? b1 : b0;
      float c1v = (e & 4) ? b3 : b2;
      float kv = (e & 8) ? c1v : c0v;
      unsigned ku = flipf(kv);
      int c = 16 * (e >> 2) + (quad << 2) + (e & 3);
      unsigned long long p = ((unsigned long long)ku << 12) | (unsigned)(gm0 + c);
      if (p < lst[KK - 1]) {
        #pragma unroll
        for (int jj = KK - 1; jj >= 1; --jj) {
          bool sh = p < lst[jj - 1];
          unsigned long long cur = (p < lst[jj]) ? p : lst[jj];
          lst[jj] = sh ? lst[jj - 1] : cur;
        }
        if (p < lst[0]) lst[0] = p;
      }
    }
  }

  // two-phase merge (rows 0-31, then 32-63): M = u64[32][84] aliases Rb (dead now)
  int orow = 16 * w + lm, oq = quad;            // owner (row, quarter)
  unsigned long long* M = (unsigned long long*)Rb;
  #pragma unroll 1
  for (int ph = 0; ph < 2; ++ph) {
    __syncthreads();
    if ((orow >> 5) == ph) {
      int r5 = orow & 31;
      #pragma unroll
      for (int k = 0; k < KK; ++k) M[r5 * 84 + oq * 21 + k] = lst[k];
      M[r5 * 84 + oq * 21 + KK] = ~0ull;
    }
    __syncthreads();
    if (t < 32) {
      int h0 = 0, h1 = 0, h2 = 0, h3 = 0;
      int rb = t * 84;
      int row = ph * 32 + t;
      size_t base = ((size_t)(b * NN + gr0 + row) * 2 + half) * KK;
      for (int k = 0; k < KK; ++k) {
        unsigned long long v0m = M[rb + h0];
        unsigned long long v1m = M[rb + 21 + h1];
        unsigned long long v2m = M[rb + 42 + h2];
        unsigned long long v3m = M[rb + 63 + h3];
        unsigned long long bv = v0m; int bq = 0;
        if (v1m < bv) { bv = v1m; bq = 1; }
        if (v2m < bv) { bv = v2m; bq = 2; }
        if (v3m < bv) { bv = v3m; bq = 3; }
        keyuG[base + k] = (unsigned)(bv >> 12);
        idxG[base + k] = (unsigned short)(bv & 0xFFFu);
        if (bq == 0) h0++; else if (bq == 1) h1++; else if (bq == 2) h2++; else h3++;
      }
    }
  }
}

__global__ __launch_bounds__(256) void k3_out(const float* __restrict__ y1,
    const float* __restrict__ y2, const unsigned* __restrict__ keyuG,
    const unsigned short* __restrict__ idxG,
    const float* __restrict__ gamma, const float* __restrict__ beta,
    const float* __restrict__ rmean, const float* __restrict__ rvar,
    float* __restrict__ out) {
  __shared__ int sidx[64 * KK];
  __shared__ float ot[64 * 65];  // [o][n], pad 65
  int t = threadIdx.x;
  int b = blockIdx.x >> 6;
  int gr0 = (blockIdx.x & 63) << 6;
  if (t < 64) {  // 2-way merge of column-half lists
    size_t base0 = ((size_t)(b * NN + gr0 + t) * 2) * KK;
    size_t base1 = base0 + KK;
    int h0 = 0, h1 = 0;
    for (int k = 0; k < KK; ++k) {
      int a0 = h0 < KK ? h0 : KK - 1;
      int a1 = h1 < KK ? h1 : KK - 1;
      unsigned k0v = keyuG[base0 + a0]; unsigned i0 = idxG[base0 + a0];
      unsigned k1v = keyuG[base1 + a1]; unsigned i1 = idxG[base1 + a1];
      bool take0 = (h1 >= KK) ||
                   ((h0 < KK) && (k0v < k1v || (k0v == k1v && i0 < i1)));
      sidx[t * KK + k] = take0 ? (int)i0 : (int)i1;
      if (take0) h0++; else h1++;
    }
  }
  int l = t & 63, w = t >> 6;
  float sc = gamma[l] * rsqrtf(rvar[l] + EPSV);
  float tt = fmaf(-rmean[l], sc, beta[l]);
  __syncthreads();
  const float* y2b = y2 + (size_t)b * NN * NO;
  for (int rr = 0; rr < 16; ++rr) {
    int row = w * 16 + rr;
    float v1 = y1[((size_t)b * NN + gr0 + row) * NO + l];
    int mk[KK];
    #pragma unroll
    for (int k = 0; k < KK; ++k) mk[k] = sidx[row * KK + k];
    float vv[KK];
    #pragma unroll
    for (int k = 0; k < KK; ++k) vv[k] = y2b[(size_t)mk[k] * NO + l];  // 20 in flight
    float best = -3.4e38f;
    #pragma unroll
    for (int k = 0; k < KK; ++k) {
      float v = v1 + vv[k];
      v = fmaf(v, sc, tt);
      v = v >= 0.f ? v : SLOPE * v;
      best = fmaxf(best, v);
    }
    ot[l * 65 + row] = best;
  }
  __syncthreads();
  float* ob = out + (size_t)b * NO * NN;
  for (int i = t; i < 4096; i += 256) {
    int o = i >> 6, n = i & 63;
    ob[(size_t)o * NN + gr0 + n] = ot[o * 65 + n];  // coalesced
  }
}

extern "C" void kernel_launch(void* const* d_in, const int* in_sizes, int n_in,
                              void* d_out, int out_size, void* d_ws, size_t ws_size,
                              hipStream_t stream) {
  const float* x     = (const float*)d_in[0];
  const float* W     = (const float*)d_in[1];
  const float* gamma = (const float*)d_in[2];
  const float* beta  = (const float*)d_in[3];
  const float* rmean = (const float*)d_in[4];
  const float* rvar  = (const float*)d_in[5];
  float* ws  = (float*)d_ws;
  float* y1    = ws;
  float* y2    = ws + 2097152;
  float* xx    = ws + 4194304;
  unsigned* keyu = (unsigned*)(ws + 4227072);
  unsigned short* idxu = (unsigned short*)(ws + 5537792);
  float* wa    = ws + 6193152;
  float* wb    = ws + 6197248;
  unsigned short* xThi  = (unsigned short*)(ws + 6201344);
  unsigned short* xTmid = (unsigned short*)(ws + 7249920);
  unsigned short* xTlo  = (unsigned short*)(ws + 8298496);
  float* out = (float*)d_out;

  hipLaunchKernelGGL(k0_wprep, dim3(1),    dim3(256), 0, stream, W, wa, wb);
  hipLaunchKernelGGL(k1_feat,  dim3(512),  dim3(256), 0, stream, x, wa, wb, y1, y2, xx,
                     xThi, xTmid, xTlo);
  hipLaunchKernelGGL(k2_topk,  dim3(1024), dim3(256), 0, stream, xThi, xTmid, xTlo,
                     xx, keyu, idxu);
  hipLaunchKernelGGL(k3_out,   dim3(512),  dim3(256), 0, stream, y1, y2, keyu, idxu,
                     gamma, beta, rmean, rvar, out);
}

// Round 6
// 375.852 us; speedup vs baseline: 1.2687x; 1.0705x over previous
//
#include <hip/hip_runtime.h>

#define NB 8
#define NC 64
#define NN 4096
#define NO 64
#define KK 20
#define EPSV 1e-5f
#define SLOPE 0.2f

typedef __attribute__((ext_vector_type(8))) short short8x;
typedef __attribute__((ext_vector_type(4))) float float4x;

// ws layout (float words):
// y1   : [B][N][O]            @0         2097152
// y2   : [B][N][O]            @2097152   2097152
// xx   : [B][N]               @4194304   32768
// keyu : [B][N][2][20] u32    @4227072   1310720
// idxu : [B][N][2][20] u16    @5537792   655360 words
// wa   : [C][O]               @6193152   4096
// wb   : [C][O]               @6197248   4096
// xThi : [B][N][C] bf16       @6201344   1048576
// xTmid: [B][N][C] bf16       @7249920   1048576
// xTlo : [B][N][C] bf16       @8298496   1048576

__device__ __forceinline__ unsigned short bfh(float f) {  // fp32 -> bf16 (RNE)
  unsigned u = __float_as_uint(f);
  unsigned r = u + 0x7FFFu + ((u >> 16) & 1u);
  return (unsigned short)(r >> 16);
}

__device__ __forceinline__ unsigned flipf(float f) {
  unsigned u = __float_as_uint(f);
  return u ^ ((unsigned)((int)u >> 31) | 0x80000000u);
}

// inverse of flipf, on raw flipped bits -> float bits
__device__ __forceinline__ unsigned unflipu(unsigned v) {
  return v ^ (0x80000000u | (unsigned)((int)(~v) >> 31));
}

__global__ void k0_wprep(const float* __restrict__ W,
                         float* __restrict__ wa, float* __restrict__ wb) {
  int t = threadIdx.x;
  for (int i = t; i < NC * NO; i += 256) {
    int o = i & 63, c = i >> 6;
    float w1 = W[o * 128 + c];
    float w2 = W[o * 128 + 64 + c];
    wa[i] = w1 - w2;  // [c][o]
    wb[i] = w2;
  }
}

__global__ __launch_bounds__(256) void k1_feat(const float* __restrict__ x,
    const float* __restrict__ waT, const float* __restrict__ wbT,
    float* __restrict__ y1, float* __restrict__ y2, float* __restrict__ xxg,
    unsigned short* __restrict__ xThi, unsigned short* __restrict__ xTmid,
    unsigned short* __restrict__ xTlo) {
  __shared__ __align__(16) float xs[NC * 68];   // [c][n] stride 68
  __shared__ __align__(16) float wa[NC * NO];
  __shared__ __align__(16) float wb[NC * NO];
  int t = threadIdx.x;
  int b = blockIdx.x >> 6;
  int gr0 = (blockIdx.x & 63) << 6;
  const float* xb = x + (size_t)b * NC * NN;
  #pragma unroll
  for (int k = 0; k < 4; ++k) {
    int i4 = t + k * 256;
    int c = i4 >> 4, col4 = (i4 & 15) << 2;
    *(float4*)&xs[c * 68 + col4] = *(const float4*)&xb[(size_t)c * NN + gr0 + col4];
    *(float4*)&wa[c * 64 + col4] = *(const float4*)&waT[c * 64 + col4];
    *(float4*)&wb[c * 64 + col4] = *(const float4*)&wbT[c * 64 + col4];
  }
  __syncthreads();
  if (t < 64) {
    float s = 0.f;
    #pragma unroll
    for (int c = 0; c < NC; ++c) { float v = xs[c * 68 + t]; s = fmaf(v, v, s); }
    xxg[b * NN + gr0 + t] = s;
  }
  int o = t & 63, w = t >> 6;
  for (int j = 0; j < 16; ++j) {
    int n = j * 4 + w;
    float a1 = 0.f, a2 = 0.f;
    #pragma unroll
    for (int c = 0; c < NC; ++c) {
      float xv = xs[c * 68 + n];
      a1 = fmaf(wa[c * 64 + o], xv, a1);
      a2 = fmaf(wb[c * 64 + o], xv, a2);
    }
    size_t base = ((size_t)b * NN + gr0 + n) * NO + o;
    y1[base] = a1;
    y2[base] = a2;
  }
  // 3-level bf16 split (REQUIRED: 2-level flips top-K selections, R10 failed),
  // transposed layout xT[b][n][c]
  int n2 = t >> 2, c0 = (t & 3) << 4;
  short8x vh[2], vm[2], vl[2];
  #pragma unroll
  for (int i = 0; i < 16; ++i) {
    float v = xs[(c0 + i) * 68 + n2];
    unsigned short h = bfh(v);
    float hf = __uint_as_float((unsigned)h << 16);
    float r1 = v - hf;
    unsigned short md = bfh(r1);
    float mf = __uint_as_float((unsigned)md << 16);
    unsigned short lo = bfh(r1 - mf);
    vh[i >> 3][i & 7] = (short)h;
    vm[i >> 3][i & 7] = (short)md;
    vl[i >> 3][i & 7] = (short)lo;
  }
  size_t tb = ((size_t)(b * NN + gr0 + n2)) * 64 + c0;
  *(short8x*)&xThi[tb] = vh[0];  *(short8x*)&xThi[tb + 8] = vh[1];
  *(short8x*)&xTmid[tb] = vm[0]; *(short8x*)&xTmid[tb + 8] = vm[1];
  *(short8x*)&xTlo[tb] = vl[0];  *(short8x*)&xTlo[tb + 8] = vl[1];
}

// ----- MFMA split-bf16 Gram + per-row exact top-K (column half) -----
// grid 1024: blk = b*128 + rowgroup*2 + half (R7-proven ordering, 34MB fetch)
//
// R11 FAILED (writer-side filter + LDS atomicOr masks): atomics added stalls.
// R12 (291us): padded candU killed swizzle math; bank conflicts 7.1M->3.9M.
// R13 FAILED on a spill (4 insert sites + key[16] under (256,3)).
// R14 (305us): spill fixed (single insert site, (256,2)) but occupancy stuck
//   at 25.7% -- compiler parked key[16]+lst in AGPRs, total regs ~>170, so
//   the structural wins (no candU, no barrier-C, -2.6M conflicts) bought no
//   TLP. Gram numerics now FROZEN (no MFMA shape/order changes: fp32 reorder
//   risks rank-20 flips -> O(1) output error, R10 lesson).
// R15 (this round): buy occupancy, not instructions.
//   - DELETE key[16]: mask built from acc and discarded; rare pop path
//     recomputes the key via 15-cndmask mux over acc + one xxs[c] b32 re-read
//     (c is exactly the xxs index).
//   - __launch_bounds__(256,3): caps allocator at ~170 regs (blocks R14's
//     bloat) while demand (~60 VGPR + 16 acc + 40 lst AGPR ~= 120) leaves
//     slack -> no spill expected, HW may even give 4 waves/SIMD.
//   Spill tripwire: WRITE_SIZE must stay ~10MB.
__global__ __launch_bounds__(256, 3) void k2_topk(
    const unsigned short* __restrict__ xThi, const unsigned short* __restrict__ xTmid,
    const unsigned short* __restrict__ xTlo, const float* __restrict__ xxg,
    unsigned* __restrict__ keyuG, unsigned short* __restrict__ idxG) {
  __shared__ __align__(16) unsigned short Rb[3 * 4096];  // 24KB staging hi/mid/lo;
                                                         // merge M u64[32*84]=21.5KB aliases
  __shared__ __align__(16) float xxs[64];

  int t = threadIdx.x;
  int blk = blockIdx.x;
  int b = blk >> 7;
  int rem = blk & 127;
  int rg = rem >> 1, half = rem & 1;
  int gr0 = rg << 6;
  int gc0 = half << 11;
  int w = t >> 6;                               // wave
  int lm = t & 15;                              // lane&15 -> row n = 16w+lm
  int quad = (t >> 4) & 3;                      // quarter: owns m ≡ 4q..4q+3 (mod 16)

  // persistent A-fragments (rows gr0+16w+lm, 3 levels x 2 k-steps)
  size_t abase = ((size_t)(b * NN + gr0 + 16 * w + lm)) * 64;
  short8x Ah[2], Am[2], Al[2];
  #pragma unroll
  for (int ks = 0; ks < 2; ++ks) {
    int co = ks * 32 + quad * 8;
    Ah[ks] = *(const short8x*)&xThi[abase + co];
    Am[ks] = *(const short8x*)&xTmid[abase + co];
    Al[ks] = *(const short8x*)&xTlo[abase + co];
  }

  unsigned long long lst[KK];                   // packed (flip(key)<<12)|m
  #pragma unroll
  for (int j = 0; j < KK; ++j) lst[j] = ~0ull;

  size_t bbase = (size_t)(b * NN) * 64;

  for (int mt = 0; mt < 32; ++mt) {
    int gm0 = gc0 + (mt << 6);
    __syncthreads();  // (A) prev tile's Rb/xxs reads done
    #pragma unroll
    for (int lvl = 0; lvl < 3; ++lvl) {
      const unsigned short* src = (lvl == 0) ? xThi : (lvl == 1) ? xTmid : xTlo;
      unsigned short* dst = Rb + lvl * 4096;
      #pragma unroll
      for (int p = 0; p < 2; ++p) {
        int idx = p * 256 + t;
        int n = idx >> 3, o = idx & 7;
        *(short8x*)&dst[n * 64 + ((o + n) & 7) * 8] =
            *(const short8x*)&src[bbase + (size_t)(gm0 + n) * 64 + o * 8];
      }
    }
    if (t < 16) *(float4*)&xxs[t * 4] = *(const float4*)&xxg[b * NN + gm0 + t * 4];
    __syncthreads();  // (B) Rb + xxs ready

    float4x acc[4];
    #pragma unroll
    for (int j = 0; j < 4; ++j) acc[j] = (float4x){0.f, 0.f, 0.f, 0.f};

    const unsigned short* RbH = Rb;
    const unsigned short* RbM = Rb + 4096;
    const unsigned short* RbL = Rb + 8192;
    #pragma unroll
    for (int ks = 0; ks < 2; ++ks) {
      #pragma unroll
      for (int j = 0; j < 4; ++j) {
        int n = 16 * j + lm;
        int off = n * 64 + ((ks * 4 + quad + n) & 7) * 8;
        short8x bh = *(const short8x*)&RbH[off];
        short8x bm = *(const short8x*)&RbM[off];
        short8x bl = *(const short8x*)&RbL[off];
        // swapped operand order (R13): D col=lane&15 = n-row, row = m-col.
        // Same product pairs/order as before -> bit-identical sums.
        acc[j] = __builtin_amdgcn_mfma_f32_16x16x32_bf16(bm, Am[ks], acc[j], 0, 0, 0);
        acc[j] = __builtin_amdgcn_mfma_f32_16x16x32_bf16(bl, Ah[ks], acc[j], 0, 0, 0);
        acc[j] = __builtin_amdgcn_mfma_f32_16x16x32_bf16(bh, Al[ks], acc[j], 0, 0, 0);
        acc[j] = __builtin_amdgcn_mfma_f32_16x16x32_bf16(bm, Ah[ks], acc[j], 0, 0, 0);
        acc[j] = __builtin_amdgcn_mfma_f32_16x16x32_bf16(bh, Am[ks], acc[j], 0, 0, 0);
        acc[j] = __builtin_amdgcn_mfma_f32_16x16x32_bf16(bh, Ah[ks], acc[j], 0, 0, 0);
      }
    }

    // per-lane: acc[j][q] = Gram(n = gr0+16w+lm, m = gm0 + 16j + 4*quad + q)
    // threshold: min over the row's 4 quad-lanes of own 20th-best (float dom.)
    unsigned own19u = (unsigned)(lst[KK - 1] >> 12);
    own19u = min(own19u, 0xFF7FFFFFu);  // clamp sentinel -> FLT_MAX, not NaN
    float thr = __uint_as_float(unflipu(own19u));
    thr = fminf(thr, __shfl_xor(thr, 16));
    thr = fminf(thr, __shfl_xor(thr, 32));

    // mask only -- keys are NOT materialized (recomputed on the rare pop path)
    unsigned mask = 0;
    #pragma unroll
    for (int j = 0; j < 4; ++j) {
      float4 xq = *(const float4*)&xxs[16 * j + 4 * quad];  // broadcast b128
      const float* xqp = (const float*)&xq;
      #pragma unroll
      for (int q = 0; q < 4; ++q) {
        float kv = fmaf(-2.f, acc[j][q], xqp[q]);
        mask |= (unsigned)(kv <= thr) << (4 * j + q);
      }
    }

    // rare path, SINGLE insert site: row-level bound guarantees any
    // final-top-20 candidate passes; exact u64 check rejects extras.
    // key recomputed: 15-cndmask mux over acc + xxs[c] re-read (c = xxs idx).
    while (mask) {
      int e = __builtin_ctz(mask);
      mask &= mask - 1;
      float a00 = (e & 1) ? acc[0][1] : acc[0][0];
      float a01 = (e & 1) ? acc[0][3] : acc[0][2];
      float a10 = (e & 1) ? acc[1][1] : acc[1][0];
      float a11 = (e & 1) ? acc[1][3] : acc[1][2];
      float a20 = (e & 1) ? acc[2][1] : acc[2][0];
      float a21 = (e & 1) ? acc[2][3] : acc[2][2];
      float a30 = (e & 1) ? acc[3][1] : acc[3][0];
      float a31 = (e & 1) ? acc[3][3] : acc[3][2];
      float b0 = (e & 2) ? a01 : a00;
      float b1 = (e & 2) ? a11 : a10;
      float b2 = (e & 2) ? a21 : a20;
      float b3 = (e & 2) ? a31 : a30;
      float c0v = (e & 4) ? b1 : b0;
      float c1v = (e & 4) ? b3 : b2;
      float av = (e & 8) ? c1v : c0v;
      int c = ((e & 12) << 2) | (quad << 2) | (e & 3);  // = m_local = xxs idx
      float kv = fmaf(-2.f, av, xxs[c]);
      unsigned ku = flipf(kv);
      unsigned long long p = ((unsigned long long)ku << 12) | (unsigned)(gm0 + c);
      if (p < lst[KK - 1]) {
        #pragma unroll
        for (int jj = KK - 1; jj >= 1; --jj) {
          bool sh = p < lst[jj - 1];
          unsigned long long cur = (p < lst[jj]) ? p : lst[jj];
          lst[jj] = sh ? lst[jj - 1] : cur;
        }
        if (p < lst[0]) lst[0] = p;
      }
    }
  }

  // two-phase merge (rows 0-31, then 32-63): M = u64[32][84] aliases Rb (dead now)
  int orow = 16 * w + lm, oq = quad;            // owner (row, quarter)
  unsigned long long* M = (unsigned long long*)Rb;
  #pragma unroll 1
  for (int ph = 0; ph < 2; ++ph) {
    __syncthreads();
    if ((orow >> 5) == ph) {
      int r5 = orow & 31;
      #pragma unroll
      for (int k = 0; k < KK; ++k) M[r5 * 84 + oq * 21 + k] = lst[k];
      M[r5 * 84 + oq * 21 + KK] = ~0ull;
    }
    __syncthreads();
    if (t < 32) {
      int h0 = 0, h1 = 0, h2 = 0, h3 = 0;
      int rb = t * 84;
      int row = ph * 32 + t;
      size_t base = ((size_t)(b * NN + gr0 + row) * 2 + half) * KK;
      for (int k = 0; k < KK; ++k) {
        unsigned long long v0m = M[rb + h0];
        unsigned long long v1m = M[rb + 21 + h1];
        unsigned long long v2m = M[rb + 42 + h2];
        unsigned long long v3m = M[rb + 63 + h3];
        unsigned long long bv = v0m; int bq = 0;
        if (v1m < bv) { bv = v1m; bq = 1; }
        if (v2m < bv) { bv = v2m; bq = 2; }
        if (v3m < bv) { bv = v3m; bq = 3; }
        keyuG[base + k] = (unsigned)(bv >> 12);
        idxG[base + k] = (unsigned short)(bv & 0xFFFu);
        if (bq == 0) h0++; else if (bq == 1) h1++; else if (bq == 2) h2++; else h3++;
      }
    }
  }
}

__global__ __launch_bounds__(256) void k3_out(const float* __restrict__ y1,
    const float* __restrict__ y2, const unsigned* __restrict__ keyuG,
    const unsigned short* __restrict__ idxG,
    const float* __restrict__ gamma, const float* __restrict__ beta,
    const float* __restrict__ rmean, const float* __restrict__ rvar,
    float* __restrict__ out) {
  __shared__ int sidx[64 * KK];
  __shared__ float ot[64 * 65];  // [o][n], pad 65
  int t = threadIdx.x;
  int b = blockIdx.x >> 6;
  int gr0 = (blockIdx.x & 63) << 6;
  if (t < 64) {  // 2-way merge of column-half lists
    size_t base0 = ((size_t)(b * NN + gr0 + t) * 2) * KK;
    size_t base1 = base0 + KK;
    int h0 = 0, h1 = 0;
    for (int k = 0; k < KK; ++k) {
      int a0 = h0 < KK ? h0 : KK - 1;
      int a1 = h1 < KK ? h1 : KK - 1;
      unsigned k0v = keyuG[base0 + a0]; unsigned i0 = idxG[base0 + a0];
      unsigned k1v = keyuG[base1 + a1]; unsigned i1 = idxG[base1 + a1];
      bool take0 = (h1 >= KK) ||
                   ((h0 < KK) && (k0v < k1v || (k0v == k1v && i0 < i1)));
      sidx[t * KK + k] = take0 ? (int)i0 : (int)i1;
      if (take0) h0++; else h1++;
    }
  }
  int l = t & 63, w = t >> 6;
  float sc = gamma[l] * rsqrtf(rvar[l] + EPSV);
  float tt = fmaf(-rmean[l], sc, beta[l]);
  __syncthreads();
  const float* y2b = y2 + (size_t)b * NN * NO;
  for (int rr = 0; rr < 16; ++rr) {
    int row = w * 16 + rr;
    float v1 = y1[((size_t)b * NN + gr0 + row) * NO + l];
    int mk[KK];
    #pragma unroll
    for (int k = 0; k < KK; ++k) mk[k] = sidx[row * KK + k];
    float vv[KK];
    #pragma unroll
    for (int k = 0; k < KK; ++k) vv[k] = y2b[(size_t)mk[k] * NO + l];  // 20 in flight
    float best = -3.4e38f;
    #pragma unroll
    for (int k = 0; k < KK; ++k) {
      float v = v1 + vv[k];
      v = fmaf(v, sc, tt);
      v = v >= 0.f ? v : SLOPE * v;
      best = fmaxf(best, v);
    }
    ot[l * 65 + row] = best;
  }
  __syncthreads();
  float* ob = out + (size_t)b * NO * NN;
  for (int i = t; i < 4096; i += 256) {
    int o = i >> 6, n = i & 63;
    ob[(size_t)o * NN + gr0 + n] = ot[o * 65 + n];  // coalesced
  }
}

extern "C" void kernel_launch(void* const* d_in, const int* in_sizes, int n_in,
                              void* d_out, int out_size, void* d_ws, size_t ws_size,
                              hipStream_t stream) {
  const float* x     = (const float*)d_in[0];
  const float* W     = (const float*)d_in[1];
  const float* gamma = (const float*)d_in[2];
  const float* beta  = (const float*)d_in[3];
  const float* rmean = (const float*)d_in[4];
  const float* rvar  = (const float*)d_in[5];
  float* ws  = (float*)d_ws;
  float* y1    = ws;
  float* y2    = ws + 2097152;
  float* xx    = ws + 4194304;
  unsigned* keyu = (unsigned*)(ws + 4227072);
  unsigned short* idxu = (unsigned short*)(ws + 5537792);
  float* wa    = ws + 6193152;
  float* wb    = ws + 6197248;
  unsigned short* xThi  = (unsigned short*)(ws + 6201344);
  unsigned short* xTmid = (unsigned short*)(ws + 7249920);
  unsigned short* xTlo  = (unsigned short*)(ws + 8298496);
  float* out = (float*)d_out;

  hipLaunchKernelGGL(k0_wprep, dim3(1),    dim3(256), 0, stream, W, wa, wb);
  hipLaunchKernelGGL(k1_feat,  dim3(512),  dim3(256), 0, stream, x, wa, wb, y1, y2, xx,
                     xThi, xTmid, xTlo);
  hipLaunchKernelGGL(k2_topk,  dim3(1024), dim3(256), 0, stream, xThi, xTmid, xTlo,
                     xx, keyu, idxu);
  hipLaunchKernelGGL(k3_out,   dim3(512),  dim3(256), 0, stream, y1, y2, keyu, idxu,
                     gamma, beta, rmean, rvar, out);
}